// Round 8
// baseline (131.727 us; speedup 1.0000x reference)
//
#include <hip/hip_runtime.h>
#include <math.h>

#define NQ   10
#define DIM  1024
#define NB   10
#define NPTS 128
#define S2   0.70710678118654752440f

#define TS 32
#define KC 64
#define KSPLIT (DIM / KC)       // 16
#define NBLK_RED 64             // reduce_final grid

// ---------------------------------------------------------------------------
// helpers
// ---------------------------------------------------------------------------
__device__ __forceinline__ void cmul_ph(float& vr, float& vi, float ph) {
    float s, c;
    __sincosf(ph, &s, &c);
    const float ar = vr, ai = vi;
    vr = ar * c - ai * s;
    vi = ar * s + ai * c;
}

__device__ __forceinline__ void cmul_cs(float& vr, float& vi, float c, float s) {
    const float ar = vr, ai = vi;
    vr = ar * c - ai * s;
    vi = ar * s + ai * c;
}

#define H_PAIR(i0, i1) {                                   \
    const float ar = vr[i0], ai = vi[i0];                  \
    const float br = vr[i1], bi = vi[i1];                  \
    vr[i0] = (ar + br) * S2;  vi[i0] = (ai + bi) * S2;     \
    vr[i1] = (ar - br) * S2;  vi[i1] = (ai - bi) * S2; }

#define RY_PAIR(i0, i1, c, s) {                            \
    const float ar = vr[i0], ai = vi[i0];                  \
    const float br = vr[i1], bi = vi[i1];                  \
    vr[i0] = c * ar - s * br;  vi[i0] = c * ai - s * bi;   \
    vr[i1] = s * ar + c * br;  vi[i1] = s * ai + c * bi; }

// ---------------------------------------------------------------------------
// Kernel A: simulate psi(x) = F(x, params)|0>.
// 1024-thread blocks, FOUR points per block (one per 256-thread quarter)
// -> 32 blocks, 16 waves/block = 4+ waves/SIMD so the dependent shuffle/barrier
// chains of 4 independent points interleave and hide each other's latency.
// Per-point logic is identical to the proven rounds 2-6 kernel (absmax 0.0):
//   canonical layout : d = w*256 + lane*4 + r   (reg bits = d-bits [1:0])
//   transposed layout: d = k*256 + lane*4 + w   (reg bits = d-bits [9:8])
// Qubit q acts on d-bit p = 9-q. Each wave is fully inside one quarter, so
// all __shfl_xor stay within a single point's state.
// ---------------------------------------------------------------------------
__global__ __launch_bounds__(1024)
void states_kernel(const float* __restrict__ data,
                   const float* __restrict__ params,
                   float2* __restrict__ psi,
                   double* __restrict__ acc,
                   int* __restrict__ cnt)
{
    __shared__ float aRe[4][DIM];
    __shared__ float aIm[4][DIM];
    __shared__ float bRe[4][DIM];
    __shared__ float bIm[4][DIM];
    __shared__ float sXb [4][NB * NQ];   // per-point data angles
    __shared__ float sRyC[NB * NQ];      // cos(ry/2)  (shared across points)
    __shared__ float sRyS[NB * NQ];      // sin(ry/2)
    __shared__ float sCrz[NB * NQ];      // crz angles
    __shared__ float sCis[4][NB][6];     // per-point RZ rotors

    const int tid  = threadIdx.x;
    const int h    = tid >> 8;           // quarter 0..3 -> which point
    const int ht   = tid & 255;          // thread id within quarter
    const int w    = ht >> 6;            // 0..3 wave-within-quarter
    const int lane = tid & 63;
    const int pt   = (blockIdx.x << 2) | h;

    const int cbase = w * 256 + lane * 4;  // canonical amps: cbase + r
    const int tb    = lane * 4 + w;        // transposed amps: k*256 + tb

    if (blockIdx.x == 0 && tid == 0) { acc[0] = 0.0; acc[1] = 0.0; cnt[0] = 0; }

    // ---------------- one-time staging ----------------
    if (ht < NB * NQ) sXb[h][ht] = data[pt * (NB * NQ) + ht];
    if (h == 0 && ht >= 100 && ht < 200) {      // params staged once
        const int t = ht - 100;                 // 0..99
        const int j = t / NQ, q = t - j * NQ;
        float s, c;
        __sincosf(0.5f * params[j * 2 * NQ + q], &s, &c);
        sRyC[t] = c; sRyS[t] = s;
        sCrz[t] = params[j * 2 * NQ + NQ + q];
    }
    __syncthreads();
    if (ht < NB) {
        const float x0 = sXb[h][ht * NQ + 0], x1 = sXb[h][ht * NQ + 1];
        float s0, c0, s1, c1;
        __sincosf(x0, &s0, &c0);
        __sincosf(x1, &s1, &c1);
        sCis[h][ht][0] = c0; sCis[h][ht][1] = s0;
        sCis[h][ht][2] = c1; sCis[h][ht][3] = s1;
        sCis[h][ht][4] = c0 * c1 - s0 * s1;
        sCis[h][ht][5] = c0 * s1 + s0 * c1;
    }
    __syncthreads();

    float vr[4], vi[4];
    vr[0] = vr[1] = vr[2] = vr[3] = 0.f;
    vi[0] = vi[1] = vi[2] = vi[3] = 0.f;
    if (ht == 0) vr[0] = 1.f;

    for (int j = 0; j < NB; ++j) {
        const int j10 = j * NQ;

        // ================= H layer =================
        H_PAIR(0, 2) H_PAIR(1, 3)
        H_PAIR(0, 1) H_PAIR(2, 3)
        #pragma unroll
        for (int l = 0; l < 6; ++l) {
            const float sg = ((lane >> l) & 1) ? -1.f : 1.f;
            #pragma unroll
            for (int r = 0; r < 4; ++r) {
                const float ur = __shfl_xor(vr[r], 1 << l, 64);
                const float ui = __shfl_xor(vi[r], 1 << l, 64);
                vr[r] = (ur + sg * vr[r]) * S2;
                vi[r] = (ui + sg * vi[r]) * S2;
            }
        }
        // transpose canonical -> transposed (buffer A)
        *(float4*)&aRe[h][cbase] = make_float4(vr[0], vr[1], vr[2], vr[3]);
        *(float4*)&aIm[h][cbase] = make_float4(vi[0], vi[1], vi[2], vi[3]);
        __syncthreads();
        #pragma unroll
        for (int k = 0; k < 4; ++k) { vr[k] = aRe[h][k * 256 + tb]; vi[k] = aIm[h][k * 256 + tb]; }
        H_PAIR(0, 2) H_PAIR(1, 3)
        H_PAIR(0, 1) H_PAIR(2, 3)

        // ================= RZ diagonal (transposed) =================
        {
            float bp = -0.5f * (sXb[h][j10 + 0] + sXb[h][j10 + 1]);
            #pragma unroll
            for (int q = 2; q < NQ; ++q)
                bp += (((tb >> (9 - q)) & 1) - 0.5f) * sXb[h][j10 + q];
            float sb, cb;
            __sincosf(bp, &sb, &cb);
            const float c0 = sCis[h][j][0], s0 = sCis[h][j][1];
            const float c1 = sCis[h][j][2], s1 = sCis[h][j][3];
            const float c01 = sCis[h][j][4], s01 = sCis[h][j][5];
            cmul_cs(vr[0], vi[0], cb, sb);
            cmul_cs(vr[1], vi[1], cb * c1 - sb * s1, sb * c1 + cb * s1);
            cmul_cs(vr[2], vi[2], cb * c0 - sb * s0, sb * c0 + cb * s0);
            cmul_cs(vr[3], vi[3], cb * c01 - sb * s01, sb * c01 + cb * s01);
        }

        // ================= RY layer =================
        {
            const float c0 = sRyC[j10 + 0], s0 = sRyS[j10 + 0];
            RY_PAIR(0, 2, c0, s0) RY_PAIR(1, 3, c0, s0)
            const float c1 = sRyC[j10 + 1], s1 = sRyS[j10 + 1];
            RY_PAIR(0, 1, c1, s1) RY_PAIR(2, 3, c1, s1)
        }
        #pragma unroll
        for (int l = 0; l < 6; ++l) {
            const float c = sRyC[j10 + 7 - l];
            const float s = sRyS[j10 + 7 - l];
            const float ss = ((lane >> l) & 1) ? s : -s;
            #pragma unroll
            for (int r = 0; r < 4; ++r) {
                const float ur = __shfl_xor(vr[r], 1 << l, 64);
                const float ui = __shfl_xor(vi[r], 1 << l, 64);
                vr[r] = c * vr[r] + ss * ur;
                vi[r] = c * vi[r] + ss * ui;
            }
        }
        // transpose back transposed -> canonical (buffer B)
        #pragma unroll
        for (int k = 0; k < 4; ++k) { bRe[h][k * 256 + tb] = vr[k]; bIm[h][k * 256 + tb] = vi[k]; }
        __syncthreads();
        {
            const float4 fr = *(const float4*)&bRe[h][cbase];
            const float4 fi = *(const float4*)&bIm[h][cbase];
            vr[0] = fr.x; vr[1] = fr.y; vr[2] = fr.z; vr[3] = fr.w;
            vi[0] = fi.x; vi[1] = fi.y; vi[2] = fi.z; vi[3] = fi.w;
        }
        {
            const float c8 = sRyC[j10 + 8], s8 = sRyS[j10 + 8];
            RY_PAIR(0, 2, c8, s8) RY_PAIR(1, 3, c8, s8)
            const float c9 = sRyC[j10 + 9], s9 = sRyS[j10 + 9];
            RY_PAIR(0, 1, c9, s9) RY_PAIR(2, 3, c9, s9)
        }

        // ================= CRZ ring diagonal (canonical) =================
        {
            const int hb = (w << 6) | lane;      // d-bits [9:2]
            float common = 0.f;
            #pragma unroll
            for (int q = 0; q <= 6; ++q) {
                const float bq  = (float)((hb >> (7 - q)) & 1);
                const float bq1 = (float)((hb >> (6 - q)) & 1);
                common += sCrz[j10 + q] * bq * (bq1 - 0.5f);
            }
            const float b2 = (float)(hb & 1);          // d-bit2
            const float b9 = (float)((hb >> 7) & 1);   // d-bit9
            const float t7 = sCrz[j10 + 7], t8 = sCrz[j10 + 8], t9 = sCrz[j10 + 9];
            #pragma unroll
            for (int r = 0; r < 4; ++r) {
                const float r1 = (float)((r >> 1) & 1);
                const float r0 = (float)(r & 1);
                const float ph = common
                               + t7 * b2 * (r1 - 0.5f)
                               + t8 * r1 * (r0 - 0.5f)
                               + t9 * r0 * (b9 - 0.5f);
                cmul_ph(vr[r], vi[r], ph);
            }
        }
    }

    float2* out = psi + pt * DIM + cbase;
    *(float4*)&out[0] = make_float4(vr[0], vi[0], vr[1], vi[1]);
    *(float4*)&out[2] = make_float4(vr[2], vi[2], vr[3], vi[3]);
}

// ---------------------------------------------------------------------------
// Kernel B: tiled complex Gram (proven rounds 2/5/6). 32x32 tile x 16 K-chunks
// = 256 blocks. Coalesced float4 staging; A broadcast / Bt <=2-way LDS reads;
// 2x2 register accumulator per thread.
// ---------------------------------------------------------------------------
__global__ __launch_bounds__(256)
void gram_kernel(const float2* __restrict__ psi, float2* __restrict__ Gpart)
{
    __shared__ float2 A [TS][KC + 2];   // pitch 66 float2
    __shared__ float2 Bt[KC][TS + 2];   // pitch 34 float2

    const int tid  = threadIdx.x;
    const int bx   = blockIdx.x;
    const int ks   = bx & 15;
    const int tile = bx >> 4;
    const int ti   = tile >> 2, tj = tile & 3;
    const int kbase = ks * KC;

    #pragma unroll
    for (int it = 0; it < 2; ++it) {
        const int slot = it * 256 + tid;
        const int row  = slot >> 4;          // 0..31
        const int kq   = (slot & 15) << 2;   // 0,4,...,60
        const float4* sa = (const float4*)(psi + (ti * TS + row) * DIM + kbase + kq);
        const float4 a01 = sa[0], a23 = sa[1];
        *(float4*)&A[row][kq]     = a01;
        *(float4*)&A[row][kq + 2] = a23;
        const float4* sb = (const float4*)(psi + (tj * TS + row) * DIM + kbase + kq);
        const float4 b01 = sb[0], b23 = sb[1];
        Bt[kq + 0][row] = make_float2(b01.x, b01.y);
        Bt[kq + 1][row] = make_float2(b01.z, b01.w);
        Bt[kq + 2][row] = make_float2(b23.x, b23.y);
        Bt[kq + 3][row] = make_float2(b23.z, b23.w);
    }
    __syncthreads();

    const int ty = tid >> 4, tx = tid & 15;
    float g00r = 0.f, g00i = 0.f, g01r = 0.f, g01i = 0.f;
    float g10r = 0.f, g10i = 0.f, g11r = 0.f, g11i = 0.f;

    #pragma unroll 4
    for (int k = 0; k < KC; k += 2) {
        const float4 a0 = *(const float4*)&A[2 * ty    ][k];
        const float4 a1 = *(const float4*)&A[2 * ty + 1][k];
        const float4 b0 = *(const float4*)&Bt[k    ][2 * tx];
        const float4 b1 = *(const float4*)&Bt[k + 1][2 * tx];
        g00r += a0.x * b0.x + a0.y * b0.y;  g00i += a0.x * b0.y - a0.y * b0.x;
        g01r += a0.x * b0.z + a0.y * b0.w;  g01i += a0.x * b0.w - a0.y * b0.z;
        g10r += a1.x * b0.x + a1.y * b0.y;  g10i += a1.x * b0.y - a1.y * b0.x;
        g11r += a1.x * b0.z + a1.y * b0.w;  g11i += a1.x * b0.w - a1.y * b0.z;
        g00r += a0.z * b1.x + a0.w * b1.y;  g00i += a0.z * b1.y - a0.w * b1.x;
        g01r += a0.z * b1.z + a0.w * b1.w;  g01i += a0.z * b1.w - a0.w * b1.z;
        g10r += a1.z * b1.x + a1.w * b1.y;  g10i += a1.z * b1.y - a1.w * b1.x;
        g11r += a1.z * b1.z + a1.w * b1.w;  g11i += a1.z * b1.w - a1.w * b1.z;
    }

    float2* gp = Gpart + ks * (NPTS * NPTS);
    const int gr0 = ti * TS + 2 * ty, gc0 = tj * TS + 2 * tx;
    gp[(gr0    ) * NPTS + gc0    ] = make_float2(g00r, g00i);
    gp[(gr0    ) * NPTS + gc0 + 1] = make_float2(g01r, g01i);
    gp[(gr0 + 1) * NPTS + gc0    ] = make_float2(g10r, g10i);
    gp[(gr0 + 1) * NPTS + gc0 + 1] = make_float2(g11r, g11i);
}

// ---------------------------------------------------------------------------
// Kernel C: sum K-partials (coalesced), K = |G|^2, reduce polarity & sum(K^2);
// last-finishing block (atomic counter, proven) writes the scalar.
// ---------------------------------------------------------------------------
__global__ __launch_bounds__(256)
void reduce_final(const float2* __restrict__ Gpart,
                  const float* __restrict__ labels,
                  double* __restrict__ acc,
                  int* __restrict__ cnt,
                  float* __restrict__ out)
{
    const int idx = blockIdx.x * 256 + threadIdx.x;   // 0..16383
    float gr = 0.f, gi = 0.f;
    #pragma unroll
    for (int p = 0; p < KSPLIT; ++p) {
        const float2 g = Gpart[p * (NPTS * NPTS) + idx];
        gr += g.x; gi += g.y;
    }
    const int i  = idx >> 7;
    const int jj = idx & (NPTS - 1);
    const float K = gr * gr + gi * gi;
    double pol = (double)(labels[i] * labels[jj]) * (double)K;
    double k2  = (double)K * (double)K;
    #pragma unroll
    for (int off = 1; off < 64; off <<= 1) {
        pol += __shfl_xor(pol, off, 64);
        k2  += __shfl_xor(k2,  off, 64);
    }
    __shared__ double sp[4], sk[4];
    const int wv = threadIdx.x >> 6;
    if ((threadIdx.x & 63) == 0) { sp[wv] = pol; sk[wv] = k2; }
    __syncthreads();
    if (threadIdx.x == 0) {
        atomicAdd(&acc[0], sp[0] + sp[1] + sp[2] + sp[3]);
        atomicAdd(&acc[1], sk[0] + sk[1] + sk[2] + sk[3]);
        __threadfence();
        const int done = atomicAdd(cnt, 1);
        if (done == NBLK_RED - 1) {
            const double p  = atomicAdd(&acc[0], 0.0);   // atomic read
            const double s2 = atomicAdd(&acc[1], 0.0);
            double sumL2 = 0.0;
            for (int t = 0; t < NPTS; ++t) {
                const double l = (double)labels[t];
                sumL2 += l * l;
            }
            out[0] = (float)(p / (sumL2 * sqrt(s2)));
        }
    }
}

// ---------------------------------------------------------------------------
extern "C" void kernel_launch(void* const* d_in, const int* in_sizes, int n_in,
                              void* d_out, int out_size, void* d_ws, size_t ws_size,
                              hipStream_t stream)
{
    const float* data   = (const float*)d_in[0];   // [128,100]
    const float* labels = (const float*)d_in[1];   // [128]
    const float* params = (const float*)d_in[2];   // [10,2,10]
    float* out = (float*)d_out;

    float2* psi   = (float2*)d_ws;                                   // 1 MiB
    float2* Gpart = (float2*)((char*)d_ws + (size_t)(1u << 20));     // 2 MiB
    double* acc   = (double*)((char*)d_ws + (size_t)(3u << 20));     // 16 B
    int*    cnt   = (int*)   ((char*)d_ws + (size_t)(3u << 20) + 16);

    states_kernel<<<NPTS / 4, 1024, 0, stream>>>(data, params, psi, acc, cnt);
    gram_kernel<<<256, 256, 0, stream>>>(psi, Gpart);
    reduce_final<<<NBLK_RED, 256, 0, stream>>>(Gpart, labels, acc, cnt, out);
}

// Round 9
// 108.939 us; speedup vs baseline: 1.2092x; 1.2092x over previous
//
#include <hip/hip_runtime.h>
#include <math.h>

#define NQ   10
#define DIM  1024
#define NB   10
#define NPTS 128
#define S2   0.70710678118654752440f

#define TS 32
#define KC 64
#define KSPLIT (DIM / KC)       // 16
#define NBLK_RED 64             // reduce_final grid

// ---------------------------------------------------------------------------
// helpers
// ---------------------------------------------------------------------------
__device__ __forceinline__ void cmul_cs(float& vr, float& vi, float c, float s) {
    const float ar = vr, ai = vi;
    vr = ar * c - ai * s;
    vi = ar * s + ai * c;
}

#define H_PAIR(i0, i1) {                                   \
    const float ar = vr[i0], ai = vi[i0];                  \
    const float br = vr[i1], bi = vi[i1];                  \
    vr[i0] = (ar + br) * S2;  vi[i0] = (ai + bi) * S2;     \
    vr[i1] = (ar - br) * S2;  vi[i1] = (ai - bi) * S2; }

#define RY_PAIR(i0, i1, c, s) {                            \
    const float ar = vr[i0], ai = vi[i0];                  \
    const float br = vr[i1], bi = vi[i1];                  \
    vr[i0] = c * ar - s * br;  vi[i0] = c * ai - s * bi;   \
    vr[i1] = s * ar + c * br;  vi[i1] = s * ai + c * bi; }

// ---------------------------------------------------------------------------
// Kernel A: simulate psi(x) = F(x, params)|0>.
// ONE WAVE (64 threads) per point, 16 amps/thread, 128 blocks.
//   canonical  layout: d = lane*16 + m   (reg bits = d[3:0], lane = d[9:4])
//   transposed layout: d = m*64  + lane  (reg bits = d[9:6], lane = d[5:0])
// Qubit q acts on d-bit 9-q.
//   - 8/10 butterfly levels are register-local (VALU only).
//   - qubits 4,5 (d bits 4,5 canonical = lane bits 1,0): __shfl_xor.
//   - transposes through a padded LDS buffer (pitch 20 floats):
//       write canonical rows b128 (lane*5 mod 8 permutes bank-quads: no
//       conflict), read/write transposed b32 (<=3-way).
//   - single wave => LDS ops FIFO-ordered => NO barriers in the main loop.
//   - diagonals: RZ = 1 sincos + 16-entry broadcast cis table;
//                CRZ = 1 sincos + 64-entry cis table (pitch 17, 4 addrs/wave).
// ---------------------------------------------------------------------------
__global__ __launch_bounds__(64)
void states_kernel(const float* __restrict__ data,
                   const float* __restrict__ params,
                   float2* __restrict__ psi,
                   double* __restrict__ acc,
                   int* __restrict__ cnt)
{
    __shared__ __align__(16) float Tre[64 * 20];   // padded transpose buffer
    __shared__ __align__(16) float Tim[64 * 20];
    __shared__ float  sX  [NB * NQ];     // data angles for this point
    __shared__ float  sRyC[NB * NQ];     // cos(ry/2)
    __shared__ float  sRyS[NB * NQ];     // sin(ry/2)
    __shared__ float  sCrz[NB * NQ];     // crz angles
    __shared__ float  sBase[NB];         // -0.5 * sum(x) per block
    __shared__ float2 sRz[NB * 16];      // RZ reg-part cis (broadcast reads)
    __shared__ float2 sRc[NB * 4 * 17];  // CRZ reg-part cis, pitch 17

    const int lane = threadIdx.x;        // 0..63 (one wave)
    const int pt   = blockIdx.x;

    if (pt == 0 && lane == 0) { acc[0] = 0.0; acc[1] = 0.0; cnt[0] = 0; }

    // ---------------- one-time staging (wave-synchronous, no barriers) ----
    for (int i = lane; i < NB * NQ; i += 64) {
        sX[i] = data[pt * (NB * NQ) + i];
        const int j = i / NQ, q = i - j * NQ;
        float s, c;
        __sincosf(0.5f * params[j * 2 * NQ + q], &s, &c);
        sRyC[i] = c; sRyS[i] = s;
        sCrz[i] = params[j * 2 * NQ + NQ + q];
    }
    if (lane < NB) {
        float s = 0.f;
        #pragma unroll
        for (int q = 0; q < NQ; ++q) s += sX[lane * NQ + q];
        sBase[lane] = -0.5f * s;
    }
    for (int e = lane; e < NB * 16; e += 64) {      // RZ tables
        const int j = e >> 4, m = e & 15;
        float T = 0.f;
        #pragma unroll
        for (int q = 0; q < 4; ++q)
            T += (float)((m >> (3 - q)) & 1) * sX[j * NQ + q];
        float s, c;
        __sincosf(T, &s, &c);
        sRz[e] = make_float2(c, s);
    }
    for (int e = lane; e < NB * 64; e += 64) {      // CRZ tables
        const int j = e >> 6, r = e & 63, bc = r >> 4, m = r & 15;
        const float b4 = (float)((bc >> 1) & 1);    // d-bit4 (lane bit 0)
        const float b9 = (float)(bc & 1);           // d-bit9 (lane bit 5)
        const float m3 = (float)((m >> 3) & 1), m2 = (float)((m >> 2) & 1);
        const float m1 = (float)((m >> 1) & 1), m0 = (float)(m & 1);
        const float g = sCrz[j * NQ + 5] * b4 * (m3 - 0.5f)
                      + sCrz[j * NQ + 6] * m3 * (m2 - 0.5f)
                      + sCrz[j * NQ + 7] * m2 * (m1 - 0.5f)
                      + sCrz[j * NQ + 8] * m1 * (m0 - 0.5f)
                      + sCrz[j * NQ + 9] * m0 * (b9 - 0.5f);
        float s, c;
        __sincosf(g, &s, &c);
        sRc[(j * 4 + bc) * 17 + m] = make_float2(c, s);
    }

    // ---------------- state init: |0...0> ----------------
    float vr[16], vi[16];
    #pragma unroll
    for (int m = 0; m < 16; ++m) { vr[m] = 0.f; vi[m] = 0.f; }
    if (lane == 0) vr[0] = 1.f;

    const int trow = (lane >> 4) * 20 + (lane & 15);   // transposed addr base

    for (int j = 0; j < NB; ++j) {
        const int j10 = j * NQ;

        // ===== H: canonical reg bits 3..0 (qubits 6..9) =====
        #pragma unroll
        for (int b = 3; b >= 0; --b) {
            const int bit = 1 << b;
            #pragma unroll
            for (int m = 0; m < 16; ++m)
                if (!(m & bit)) { H_PAIR(m, m | bit) }
        }
        // ===== H: lane bits 0,1 (qubits 5,4) via shuffle =====
        #pragma unroll
        for (int l = 0; l < 2; ++l) {
            const float sg = ((lane >> l) & 1) ? -1.f : 1.f;
            #pragma unroll
            for (int m = 0; m < 16; ++m) {
                const float ur = __shfl_xor(vr[m], 1 << l, 64);
                const float ui = __shfl_xor(vi[m], 1 << l, 64);
                vr[m] = (ur + sg * vr[m]) * S2;
                vi[m] = (ui + sg * vi[m]) * S2;
            }
        }
        // ===== transpose canonical -> transposed =====
        #pragma unroll
        for (int k = 0; k < 4; ++k) {
            *(float4*)&Tre[lane * 20 + 4 * k] = make_float4(vr[4*k], vr[4*k+1], vr[4*k+2], vr[4*k+3]);
            *(float4*)&Tim[lane * 20 + 4 * k] = make_float4(vi[4*k], vi[4*k+1], vi[4*k+2], vi[4*k+3]);
        }
        #pragma unroll
        for (int m = 0; m < 16; ++m) {
            vr[m] = Tre[m * 80 + trow];
            vi[m] = Tim[m * 80 + trow];
        }
        // ===== H: transposed reg bits 3..0 (qubits 0..3) =====
        #pragma unroll
        for (int b = 3; b >= 0; --b) {
            const int bit = 1 << b;
            #pragma unroll
            for (int m = 0; m < 16; ++m)
                if (!(m & bit)) { H_PAIR(m, m | bit) }
        }

        // ===== RZ diagonal (transposed) =====
        {
            float lp = sBase[j];
            #pragma unroll
            for (int q = 4; q < NQ; ++q)
                lp = fmaf((float)((lane >> (9 - q)) & 1), sX[j10 + q], lp);
            float sl, cl;
            __sincosf(lp, &sl, &cl);
            #pragma unroll
            for (int m = 0; m < 16; ++m) {
                const float2 z = sRz[j * 16 + m];
                const float rc = cl * z.x - sl * z.y;
                const float rs = cl * z.y + sl * z.x;
                cmul_cs(vr[m], vi[m], rc, rs);
            }
        }

        // ===== RY: transposed reg bits (qubit q <-> bit 3-q), q=0..3 =====
        #pragma unroll
        for (int q = 0; q < 4; ++q) {
            const float c = sRyC[j10 + q], s = sRyS[j10 + q];
            const int bit = 1 << (3 - q);
            #pragma unroll
            for (int m = 0; m < 16; ++m)
                if (!(m & bit)) { RY_PAIR(m, m | bit, c, s) }
        }
        // ===== transpose back transposed -> canonical =====
        #pragma unroll
        for (int m = 0; m < 16; ++m) {
            Tre[m * 80 + trow] = vr[m];
            Tim[m * 80 + trow] = vi[m];
        }
        #pragma unroll
        for (int k = 0; k < 4; ++k) {
            const float4 fr = *(const float4*)&Tre[lane * 20 + 4 * k];
            const float4 fi = *(const float4*)&Tim[lane * 20 + 4 * k];
            vr[4*k] = fr.x; vr[4*k+1] = fr.y; vr[4*k+2] = fr.z; vr[4*k+3] = fr.w;
            vi[4*k] = fi.x; vi[4*k+1] = fi.y; vi[4*k+2] = fi.z; vi[4*k+3] = fi.w;
        }
        // ===== RY: canonical reg bits (qubit q <-> bit 9-q), q=6..9 =====
        #pragma unroll
        for (int q = 6; q < 10; ++q) {
            const float c = sRyC[j10 + q], s = sRyS[j10 + q];
            const int bit = 1 << (9 - q);
            #pragma unroll
            for (int m = 0; m < 16; ++m)
                if (!(m & bit)) { RY_PAIR(m, m | bit, c, s) }
        }
        // ===== RY: lane bits 0,1 (qubits 5,4) via shuffle =====
        #pragma unroll
        for (int l = 0; l < 2; ++l) {
            const float c = sRyC[j10 + 5 - l];
            const float s = sRyS[j10 + 5 - l];
            const float ss = ((lane >> l) & 1) ? s : -s;
            #pragma unroll
            for (int m = 0; m < 16; ++m) {
                const float ur = __shfl_xor(vr[m], 1 << l, 64);
                const float ui = __shfl_xor(vi[m], 1 << l, 64);
                vr[m] = c * vr[m] + ss * ur;
                vi[m] = c * vi[m] + ss * ui;
            }
        }

        // ===== CRZ ring diagonal (canonical) =====
        {
            float cm = 0.f;
            #pragma unroll
            for (int q = 0; q <= 4; ++q) {
                const float bc_ = (float)((lane >> (5 - q)) & 1);
                const float bt_ = (float)((lane >> (4 - q)) & 1);
                cm += sCrz[j10 + q] * bc_ * (bt_ - 0.5f);
            }
            float sc, cc;
            __sincosf(cm, &sc, &cc);
            const int bc = ((lane & 1) << 1) | ((lane >> 5) & 1);
            const float2* __restrict__ rcp = &sRc[(j * 4 + bc) * 17];
            #pragma unroll
            for (int m = 0; m < 16; ++m) {
                const float2 z = rcp[m];
                const float rr = cc * z.x - sc * z.y;
                const float ri = cc * z.y + sc * z.x;
                cmul_cs(vr[m], vi[m], rr, ri);
            }
        }
    }

    // ---------------- write out (canonical) ----------------
    float2* o = psi + (size_t)pt * DIM + lane * 16;
    #pragma unroll
    for (int k = 0; k < 8; ++k)
        *(float4*)&o[2 * k] = make_float4(vr[2*k], vi[2*k], vr[2*k+1], vi[2*k+1]);
}

// ---------------------------------------------------------------------------
// Kernel B: tiled complex Gram (proven rounds 2/5/6). 32x32 tile x 16 K-chunks
// = 256 blocks. Coalesced float4 staging; A broadcast / Bt <=2-way LDS reads;
// 2x2 register accumulator per thread.
// ---------------------------------------------------------------------------
__global__ __launch_bounds__(256)
void gram_kernel(const float2* __restrict__ psi, float2* __restrict__ Gpart)
{
    __shared__ float2 A [TS][KC + 2];   // pitch 66 float2
    __shared__ float2 Bt[KC][TS + 2];   // pitch 34 float2

    const int tid  = threadIdx.x;
    const int bx   = blockIdx.x;
    const int ks   = bx & 15;
    const int tile = bx >> 4;
    const int ti   = tile >> 2, tj = tile & 3;
    const int kbase = ks * KC;

    #pragma unroll
    for (int it = 0; it < 2; ++it) {
        const int slot = it * 256 + tid;
        const int row  = slot >> 4;          // 0..31
        const int kq   = (slot & 15) << 2;   // 0,4,...,60
        const float4* sa = (const float4*)(psi + (ti * TS + row) * DIM + kbase + kq);
        const float4 a01 = sa[0], a23 = sa[1];
        *(float4*)&A[row][kq]     = a01;
        *(float4*)&A[row][kq + 2] = a23;
        const float4* sb = (const float4*)(psi + (tj * TS + row) * DIM + kbase + kq);
        const float4 b01 = sb[0], b23 = sb[1];
        Bt[kq + 0][row] = make_float2(b01.x, b01.y);
        Bt[kq + 1][row] = make_float2(b01.z, b01.w);
        Bt[kq + 2][row] = make_float2(b23.x, b23.y);
        Bt[kq + 3][row] = make_float2(b23.z, b23.w);
    }
    __syncthreads();

    const int ty = tid >> 4, tx = tid & 15;
    float g00r = 0.f, g00i = 0.f, g01r = 0.f, g01i = 0.f;
    float g10r = 0.f, g10i = 0.f, g11r = 0.f, g11i = 0.f;

    #pragma unroll 4
    for (int k = 0; k < KC; k += 2) {
        const float4 a0 = *(const float4*)&A[2 * ty    ][k];
        const float4 a1 = *(const float4*)&A[2 * ty + 1][k];
        const float4 b0 = *(const float4*)&Bt[k    ][2 * tx];
        const float4 b1 = *(const float4*)&Bt[k + 1][2 * tx];
        g00r += a0.x * b0.x + a0.y * b0.y;  g00i += a0.x * b0.y - a0.y * b0.x;
        g01r += a0.x * b0.z + a0.y * b0.w;  g01i += a0.x * b0.w - a0.y * b0.z;
        g10r += a1.x * b0.x + a1.y * b0.y;  g10i += a1.x * b0.y - a1.y * b0.x;
        g11r += a1.x * b0.z + a1.y * b0.w;  g11i += a1.x * b0.w - a1.y * b0.z;
        g00r += a0.z * b1.x + a0.w * b1.y;  g00i += a0.z * b1.y - a0.w * b1.x;
        g01r += a0.z * b1.z + a0.w * b1.w;  g01i += a0.z * b1.w - a0.w * b1.z;
        g10r += a1.z * b1.x + a1.w * b1.y;  g10i += a1.z * b1.y - a1.w * b1.x;
        g11r += a1.z * b1.z + a1.w * b1.w;  g11i += a1.z * b1.w - a1.w * b1.z;
    }

    float2* gp = Gpart + ks * (NPTS * NPTS);
    const int gr0 = ti * TS + 2 * ty, gc0 = tj * TS + 2 * tx;
    gp[(gr0    ) * NPTS + gc0    ] = make_float2(g00r, g00i);
    gp[(gr0    ) * NPTS + gc0 + 1] = make_float2(g01r, g01i);
    gp[(gr0 + 1) * NPTS + gc0    ] = make_float2(g10r, g10i);
    gp[(gr0 + 1) * NPTS + gc0 + 1] = make_float2(g11r, g11i);
}

// ---------------------------------------------------------------------------
// Kernel C: sum K-partials (coalesced), K = |G|^2, reduce polarity & sum(K^2);
// last-finishing block (atomic counter, proven) writes the scalar.
// ---------------------------------------------------------------------------
__global__ __launch_bounds__(256)
void reduce_final(const float2* __restrict__ Gpart,
                  const float* __restrict__ labels,
                  double* __restrict__ acc,
                  int* __restrict__ cnt,
                  float* __restrict__ out)
{
    const int idx = blockIdx.x * 256 + threadIdx.x;   // 0..16383
    float gr = 0.f, gi = 0.f;
    #pragma unroll
    for (int p = 0; p < KSPLIT; ++p) {
        const float2 g = Gpart[p * (NPTS * NPTS) + idx];
        gr += g.x; gi += g.y;
    }
    const int i  = idx >> 7;
    const int jj = idx & (NPTS - 1);
    const float K = gr * gr + gi * gi;
    double pol = (double)(labels[i] * labels[jj]) * (double)K;
    double k2  = (double)K * (double)K;
    #pragma unroll
    for (int off = 1; off < 64; off <<= 1) {
        pol += __shfl_xor(pol, off, 64);
        k2  += __shfl_xor(k2,  off, 64);
    }
    __shared__ double sp[4], sk[4];
    const int wv = threadIdx.x >> 6;
    if ((threadIdx.x & 63) == 0) { sp[wv] = pol; sk[wv] = k2; }
    __syncthreads();
    if (threadIdx.x == 0) {
        atomicAdd(&acc[0], sp[0] + sp[1] + sp[2] + sp[3]);
        atomicAdd(&acc[1], sk[0] + sk[1] + sk[2] + sk[3]);
        __threadfence();
        const int done = atomicAdd(cnt, 1);
        if (done == NBLK_RED - 1) {
            const double p  = atomicAdd(&acc[0], 0.0);   // atomic read
            const double s2 = atomicAdd(&acc[1], 0.0);
            double sumL2 = 0.0;
            for (int t = 0; t < NPTS; ++t) {
                const double l = (double)labels[t];
                sumL2 += l * l;
            }
            out[0] = (float)(p / (sumL2 * sqrt(s2)));
        }
    }
}

// ---------------------------------------------------------------------------
extern "C" void kernel_launch(void* const* d_in, const int* in_sizes, int n_in,
                              void* d_out, int out_size, void* d_ws, size_t ws_size,
                              hipStream_t stream)
{
    const float* data   = (const float*)d_in[0];   // [128,100]
    const float* labels = (const float*)d_in[1];   // [128]
    const float* params = (const float*)d_in[2];   // [10,2,10]
    float* out = (float*)d_out;

    float2* psi   = (float2*)d_ws;                                   // 1 MiB
    float2* Gpart = (float2*)((char*)d_ws + (size_t)(1u << 20));     // 2 MiB
    double* acc   = (double*)((char*)d_ws + (size_t)(3u << 20));     // 16 B
    int*    cnt   = (int*)   ((char*)d_ws + (size_t)(3u << 20) + 16);

    states_kernel<<<NPTS, 64, 0, stream>>>(data, params, psi, acc, cnt);
    gram_kernel<<<256, 256, 0, stream>>>(psi, Gpart);
    reduce_final<<<NBLK_RED, 256, 0, stream>>>(Gpart, labels, acc, cnt, out);
}